// Round 1
// baseline (2614.344 us; speedup 1.0000x reference)
//
#include <hip/hip_runtime.h>

#define ALPHA_C 0.05f
#define BETA_C  0.95f
#define GAMMA_C 0.95f

constexpr int B = 16, T = 24, N = 512, F = 2, H = 64, E = 16;
constexpr int DA = 8;        // D_ATTN
constexpr int CC = F + H;    // 66
constexpr int TGN_OC = 32;

__device__ __forceinline__ float fast_tanh(float x) {
    // 1 - 2/(e^{2x}+1): saturates correctly at +-1 for large |x|
    return 1.0f - 2.0f / (__expf(2.0f * x) + 1.0f);
}
__device__ __forceinline__ float fast_sigmoid(float x) {
    return 1.0f / (1.0f + __expf(-x));
}

// ---------------------------------------------------------------------------
// Batched graph-conv matmul:
//   out[b,w,c] = ALPHA*x[b,w,c] + sum_v ( GAMMA*MA[v,w] (+ BETA*MB[b,v,w]) ) * h[b,v,c]
// MA is shared (predefined_A), MB is per-batch (adp). M tiles are transposed
// in-LDS so global reads stay coalesced along w.
// Block: 256 threads, W-tile 32, V-tile 64. thread: wl=tid>>3, cg=tid&7,
// columns c = cg + 8k.
// ---------------------------------------------------------------------------
template<int C, int NC, bool TWOM>
__global__ __launch_bounds__(256) void bmm_kernel(
    float* __restrict__ out, const float* __restrict__ x, const float* __restrict__ h,
    const float* __restrict__ MA, const float* __restrict__ MB)
{
    constexpr int WT = 32, VT = 64;
    constexpr int CP = (NC * 8 > C) ? (NC * 8) : C;   // padded col count
    __shared__ float sh_mA[WT][VT + 1];
    __shared__ float sh_mB[TWOM ? WT : 1][VT + 1];
    __shared__ float sh_h[VT][CP + 2];

    const int b  = blockIdx.y;
    const int w0 = blockIdx.x * WT;
    const int tid = threadIdx.x;
    const int wl = tid >> 3;    // 0..31
    const int cg = tid & 7;     // 0..7

    float acc[NC];
#pragma unroll
    for (int k = 0; k < NC; ++k) acc[k] = 0.0f;

    if (CP > C) {  // zero pad columns once (constexpr-guarded)
        for (int l = tid; l < VT * (CP - C); l += 256)
            sh_h[l / (CP - C)][C + (l % (CP - C))] = 0.0f;
    }
    __syncthreads();

    const float* Mb = TWOM ? (MB + (size_t)b * N * N) : MA;
    const float* hb = h + (size_t)b * N * C;

    for (int vt = 0; vt < N / VT; ++vt) {
        const int v0 = vt * VT;
#pragma unroll
        for (int it = 0; it < (WT * VT) / 256; ++it) {
            int l = it * 256 + tid;
            int vr = l >> 5;          // 0..63
            int wc = l & 31;          // 0..31
            sh_mA[wc][vr] = MA[(size_t)(v0 + vr) * N + (w0 + wc)];
        }
        if (TWOM) {
#pragma unroll
            for (int it = 0; it < (WT * VT) / 256; ++it) {
                int l = it * 256 + tid;
                int vr = l >> 5;
                int wc = l & 31;
                sh_mB[wc][vr] = Mb[(size_t)(v0 + vr) * N + (w0 + wc)];
            }
        }
        for (int l = tid; l < VT * C; l += 256) {
            int r = l / C, col = l % C;
            sh_h[r][col] = hb[(size_t)v0 * C + l];   // contiguous -> coalesced
        }
        __syncthreads();
#pragma unroll 4
        for (int j = 0; j < VT; ++j) {
            float mj;
            if (TWOM) mj = BETA_C * sh_mB[wl][j] + GAMMA_C * sh_mA[wl][j];
            else      mj = GAMMA_C * sh_mA[wl][j];
#pragma unroll
            for (int k = 0; k < NC; ++k)
                acc[k] += mj * sh_h[j][cg + 8 * k];
        }
        __syncthreads();
    }
    const size_t rowbase = ((size_t)b * N + w0 + wl) * C;
#pragma unroll
    for (int k = 0; k < NC; ++k) {
        int c = cg + 8 * k;
        if (c < C) out[rowbase + c] = ALPHA_C * x[rowbase + c] + acc[k];
    }
}

// ---------------------------------------------------------------------------
// gs/gt + node embeddings fused: one thread per (b,n,e), e<16.
// gs = b_agg1[e] + sum_{s<3,k<64} seg_s[b,n,k] * W_agg1[(s*64+k)*16+e]  (gt same)
// nv_s = tanh(2*(graph@W_srcemb + b_srcemb)*gs), nv_t analogous.
// ---------------------------------------------------------------------------
__global__ __launch_bounds__(256) void gsgt_nv_kernel(
    const float* __restrict__ hidden, const float* __restrict__ hh1, const float* __restrict__ hh2,
    const float* __restrict__ Wa1, const float* __restrict__ ba1,
    const float* __restrict__ Wa2, const float* __restrict__ ba2,
    const float* __restrict__ graph, long gstride,
    const float* __restrict__ Wsrc, const float* __restrict__ bsrc,
    const float* __restrict__ Wtgt, const float* __restrict__ btgt,
    float* __restrict__ nv_s, float* __restrict__ nv_t)
{
    int idx = blockIdx.x * 256 + threadIdx.x;   // B*N*E
    int e = idx & 15;
    int n = (idx >> 4) & (N - 1);
    int b = idx >> 13;
    const float* segs[3] = {hidden, hh1, hh2};
    float gs = ba1[e], gt = ba2[e];
    size_t row = ((size_t)b * N + n) * H;
    for (int s = 0; s < 3; ++s) {
        const float* hp = segs[s] + row;
        const float* w1 = Wa1 + (size_t)(s * H) * E + e;
        const float* w2 = Wa2 + (size_t)(s * H) * E + e;
        for (int k = 0; k < H; ++k) {
            float v = hp[k];
            gs += v * w1[(size_t)k * E];
            gt += v * w2[(size_t)k * E];
        }
    }
    const float* g = graph + (size_t)b * gstride + (size_t)n * F;
    float g0 = g[0], g1 = g[1];
    float es = g0 * Wsrc[e] + g1 * Wsrc[E + e] + bsrc[e];
    float et = g0 * Wtgt[e] + g1 * Wtgt[E + e] + btgt[e];
    size_t o = ((size_t)b * N + n) * E + e;
    nv_s[o] = fast_tanh(2.0f * es * gs);
    nv_t[o] = fast_tanh(2.0f * et * gt);
}

// ---------------------------------------------------------------------------
// adp row builder: one 512-thread block per (b,n) row.
// a[n,m] = <nv_s[n],nv_t[m]> - <nv_t[n],nv_s[m]>;
// P = relu(tanh(2a)) + I; adp[n,:] = P / rowsum(P).
// ---------------------------------------------------------------------------
__global__ __launch_bounds__(512) void adp_kernel(
    const float* __restrict__ nv_s, const float* __restrict__ nv_t, float* __restrict__ adp)
{
    __shared__ float red[8];
    int n = blockIdx.x, b = blockIdx.y, m = threadIdx.x;
    const float* sn = nv_s + ((size_t)b * N + n) * E;
    const float* tn = nv_t + ((size_t)b * N + n) * E;
    const float* sm = nv_s + ((size_t)b * N + m) * E;
    const float* tm = nv_t + ((size_t)b * N + m) * E;
    float a1 = 0.f, a2 = 0.f;
#pragma unroll
    for (int d = 0; d < E; ++d) { a1 += sn[d] * tm[d]; a2 += tn[d] * sm[d]; }
    float p = fast_tanh(2.0f * (a1 - a2));
    p = fmaxf(p, 0.0f);
    if (m == n) p += 1.0f;
    float s = p;
    for (int o = 32; o > 0; o >>= 1) s += __shfl_down(s, o);
    int wid = m >> 6, lane = m & 63;
    if (lane == 0) red[wid] = s;
    __syncthreads();
    if (m == 0) { float t = 0.f; for (int i = 0; i < 8; ++i) t += red[i]; red[0] = t; }
    __syncthreads();
    adp[((size_t)b * N + n) * N + m] = p / red[0];
}

// combined = concat([graph, hidden], -1)  -> (B,N,66)
__global__ void concat_kernel(const float* __restrict__ graph, long gstride,
                              const float* __restrict__ hidden, float* __restrict__ comb)
{
    int idx = blockIdx.x * 256 + threadIdx.x;   // B*N*CC
    int k = idx % CC;
    int nn = idx / CC;                           // b*N+n
    int n = nn & (N - 1);
    int b = nn >> 9;
    float v;
    if (k < F) v = graph[(size_t)b * gstride + (size_t)n * F + k];
    else       v = hidden[(size_t)nn * H + (k - F)];
    comb[idx] = v;
}

// z,r small matmuls + build combined2 = [graph, r*hidden]
__global__ __launch_bounds__(256) void zr_kernel(
    const float* __restrict__ comb, const float* __restrict__ hr1, const float* __restrict__ hr2,
    const float* __restrict__ Wgz, const float* __restrict__ bgz,
    const float* __restrict__ Wgr, const float* __restrict__ bgr,
    const float* __restrict__ hidden, const float* __restrict__ graph, long gstride,
    float* __restrict__ z, float* __restrict__ comb2)
{
    int idx = blockIdx.x * 256 + threadIdx.x;   // B*N*H
    int oc = idx & 63;
    int n = (idx >> 6) & (N - 1);
    int b = idx >> 15;
    const float* segs[3] = {comb, hr1, hr2};
    float az = bgz[oc], ar = bgr[oc];
    size_t nn = (size_t)b * N + n;
    for (int s = 0; s < 3; ++s) {
        const float* hp = segs[s] + nn * CC;
        const float* w1 = Wgz + (size_t)(s * CC) * H + oc;
        const float* w2 = Wgr + (size_t)(s * CC) * H + oc;
        for (int k = 0; k < CC; ++k) {
            float v = hp[k];
            az += v * w1[(size_t)k * H];
            ar += v * w2[(size_t)k * H];
        }
    }
    float zv = fast_sigmoid(az), rv = fast_sigmoid(ar);
    z[nn * H + oc] = zv;
    comb2[nn * CC + F + oc] = rv * hidden[nn * H + oc];
    if (oc < F) comb2[nn * CC + oc] = graph[(size_t)b * gstride + (size_t)n * F + oc];
}

// c = tanh(cat([comb2,hc1,hc2]) @ W_gc + b_gc); hidden = z*hidden + (1-z)*c
__global__ __launch_bounds__(256) void c_update_kernel(
    const float* __restrict__ comb2, const float* __restrict__ hc1, const float* __restrict__ hc2,
    const float* __restrict__ Wgc, const float* __restrict__ bgc,
    const float* __restrict__ z, float* __restrict__ hidden)
{
    int idx = blockIdx.x * 256 + threadIdx.x;   // B*N*H
    int oc = idx & 63;
    int n = (idx >> 6) & (N - 1);
    int b = idx >> 15;
    const float* segs[3] = {comb2, hc1, hc2};
    float ac = bgc[oc];
    size_t nn = (size_t)b * N + n;
    for (int s = 0; s < 3; ++s) {
        const float* hp = segs[s] + nn * CC;
        const float* w1 = Wgc + (size_t)(s * CC) * H + oc;
        for (int k = 0; k < CC; ++k) ac += hp[k] * w1[(size_t)k * H];
    }
    float cv = fast_tanh(ac);
    float zv = z[nn * H + oc];
    float ho = hidden[nn * H + oc];
    hidden[nn * H + oc] = zv * ho + (1.0f - zv) * cv;
}

// q[b,n,d] = tar@w_query + bias (bias folded); kk[b,t,n,d] = src@w_key
__global__ void qk_kernel(const float* __restrict__ sample,
                          const float* __restrict__ wq, const float* __restrict__ wk,
                          const float* __restrict__ attn_bias,
                          float* __restrict__ q, float* __restrict__ kk)
{
    int idx = blockIdx.x * 256 + threadIdx.x;
    if (idx < B * N * DA) {
        int d = idx & 7;
        int n = (idx >> 3) & (N - 1);
        int b = idx >> 12;
        const float* tar = sample + (((size_t)b * T + (T - 1)) * N + n) * F;
        q[idx] = tar[0] * wq[d] + tar[1] * wq[DA + d] + attn_bias[d];
    } else {
        int j = idx - B * N * DA;   // B*4*N*DA
        int d = j & 7;
        int n = (j >> 3) & (N - 1);
        int t = (j >> 12) & 3;
        int b = j >> 14;
        const float* s = sample + (((size_t)b * T + (T - 4 + t)) * N + n) * F;
        kk[j] = s[0] * wk[d] + s[1] * wk[DA + d];
    }
}

// scores + softmax over m; writes attn (B,4,N,N) into d_out
__global__ __launch_bounds__(512) void scores_kernel(
    const float* __restrict__ q, const float* __restrict__ kk,
    const float* __restrict__ trans, float* __restrict__ attn)
{
    __shared__ float red[8];
    int n = blockIdx.x, t = blockIdx.y, b = blockIdx.z, m = threadIdx.x;
    const float* qp = q + ((size_t)b * N + n) * DA;
    const float* kp = kk + (((size_t)(b * 4 + t)) * N + m) * DA;
    float s = 0.f;
#pragma unroll
    for (int d = 0; d < DA; ++d) s += fast_tanh(qp[d] + kp[d]) * trans[d];
    float mx = s;
    for (int o = 32; o > 0; o >>= 1) mx = fmaxf(mx, __shfl_down(mx, o));
    int wid = m >> 6, lane = m & 63;
    if (lane == 0) red[wid] = mx;
    __syncthreads();
    if (m == 0) { float r = red[0]; for (int i = 1; i < 8; ++i) r = fmaxf(r, red[i]); red[0] = r; }
    __syncthreads();
    mx = red[0];
    __syncthreads();
    float e = __expf(s - mx);
    float ss = e;
    for (int o = 32; o > 0; o >>= 1) ss += __shfl_down(ss, o);
    if (lane == 0) red[wid] = ss;
    __syncthreads();
    if (m == 0) { float r = 0.f; for (int i = 0; i < 8; ++i) r += red[i]; red[0] = r; }
    __syncthreads();
    attn[(((size_t)(b * 4 + t)) * N + n) * N + m] = e / red[0];
}

// TGN conv: out[bt,w,c] = 0.05*x + 0.95*sum_v (A[v,w]+attn[bt,v,w]) * h[bt,v,c]
// h/x addressed via base + (bt>>2)*sB + (bt&3)*sT (+ v*F + c) to unify
// sample-strided and contiguous operands.
__global__ __launch_bounds__(128) void tgn_mm_kernel(
    const float* __restrict__ A, const float* __restrict__ attn,
    const float* __restrict__ hbase, long hsB, long hsT,
    const float* __restrict__ xbase, long xsB, long xsT,
    float* __restrict__ out)
{
    __shared__ float sh_m[64][65];
    __shared__ float sh_h[64][2];
    int bt = blockIdx.y;
    int w0 = blockIdx.x * 64;
    int tid = threadIdx.x;
    int wl = tid >> 1, c = tid & 1;
    const float* hp = hbase + (size_t)(bt >> 2) * hsB + (size_t)(bt & 3) * hsT;
    const float* ap = attn + (size_t)bt * N * N;
    float acc = 0.f;
    for (int vt = 0; vt < 8; ++vt) {
        int v0 = vt * 64;
#pragma unroll
        for (int it = 0; it < 32; ++it) {
            int l = it * 128 + tid;
            int vr = l >> 6;
            int wc = l & 63;
            size_t gi = (size_t)(v0 + vr) * N + (w0 + wc);
            sh_m[wc][vr] = A[gi] + ap[gi];
        }
        {
            int r = tid >> 1, cc = tid & 1;
            sh_h[r][cc] = hp[(size_t)(v0 + r) * F + cc];
        }
        __syncthreads();
#pragma unroll 8
        for (int j = 0; j < 64; ++j) acc += sh_m[wl][j] * sh_h[j][c];
        __syncthreads();
    }
    const float* xp = xbase + (size_t)(bt >> 2) * xsB + (size_t)(bt & 3) * xsT;
    out[((size_t)bt * N + w0 + wl) * F + c] =
        ALPHA_C * xp[(size_t)(w0 + wl) * F + c] + GAMMA_C * acc;
}

// relu(cat @ W_tgn + b) summed over t -> tar32 (B,N,32)
__global__ void tgn_out_kernel(const float* __restrict__ sample,
                               const float* __restrict__ th1, const float* __restrict__ th2,
                               const float* __restrict__ Wt, const float* __restrict__ bt_,
                               float* __restrict__ tar32)
{
    int idx = blockIdx.x * 256 + threadIdx.x;  // B*N*32
    int oc = idx & 31;
    int n = (idx >> 5) & (N - 1);
    int b = idx >> 14;
    float acc = 0.f;
    for (int t = 0; t < 4; ++t) {
        int bt = b * 4 + t;
        const float* s = sample + (((size_t)b * T + (T - 4 + t)) * N + n) * F;
        size_t r = ((size_t)bt * N + n) * F;
        float v = bt_[oc];
        v += s[0] * Wt[0 * TGN_OC + oc] + s[1] * Wt[1 * TGN_OC + oc];
        v += th1[r] * Wt[2 * TGN_OC + oc] + th1[r + 1] * Wt[3 * TGN_OC + oc];
        v += th2[r] * Wt[4 * TGN_OC + oc] + th2[r + 1] * Wt[5 * TGN_OC + oc];
        acc += fmaxf(v, 0.0f);
    }
    tar32[idx] = acc;
}

__global__ void gat_kernel(const float* __restrict__ tar32,
                           const float* __restrict__ Ws, const float* __restrict__ bs,
                           float* __restrict__ out0)
{
    int idx = blockIdx.x * 256 + threadIdx.x;  // B*N*F
    int f = idx & 1;
    int nn = idx >> 1;
    float acc = bs[f];
    const float* tp = tar32 + (size_t)nn * TGN_OC;
    for (int k = 0; k < TGN_OC; ++k) acc += tp[k] * Ws[(size_t)k * F + f];
    out0[idx] = acc;
}

// gru_result + final_result
__global__ void final_kernel(const float* __restrict__ hidden, const float* __restrict__ tar32,
                             const float* __restrict__ Wl, const float* __restrict__ bl,
                             const float* __restrict__ Wm, const float* __restrict__ bm,
                             float* __restrict__ dout_gru, float* __restrict__ dout_fin)
{
    int idx = blockIdx.x * 256 + threadIdx.x;  // B*N*F
    int f = idx & 1;
    int nn = idx >> 1;
    const float* hp = hidden + (size_t)nn * H;
    const float* tp = tar32 + (size_t)nn * TGN_OC;
    float g = bl[f], fin = bm[f];
    for (int k = 0; k < H; ++k) g += hp[k] * Wl[(size_t)k * F + f];
    for (int k = 0; k < TGN_OC; ++k) fin += tp[k] * Wm[(size_t)k * F + f];
    for (int k = 0; k < H; ++k) fin += hp[k] * Wm[(size_t)(TGN_OC + k) * F + f];
    dout_gru[idx] = g;
    dout_fin[idx] = fin;
}

// ---------------------------------------------------------------------------
// Host side
// ---------------------------------------------------------------------------
namespace {
struct Ptrs {
    const float *sample, *A, *wq, *wk, *attn_bias, *attn_trans, *Wt, *bt_;
    const float *Wa1, *ba1, *Wa2, *ba2, *Wsrc, *bsrc, *Wtgt, *btgt;
    const float *Wgz, *bgz, *Wgr, *bgr, *Wgc, *bgc, *Wsh, *bsh, *Wl, *bl, *Wm, *bm;
    float *hidden, *hh1, *hh2, *nvs, *nvt, *adp, *comb, *hr1, *hr2, *z, *comb2;
    float *q, *kk, *th1, *th2, *tar32;
};

void gru_step(hipStream_t stream, const Ptrs& p, const float* graph, long gstride)
{
    dim3 bg(N / 32, B);
    bmm_kernel<H, 8, false><<<bg, 256, 0, stream>>>(p.hh1, p.hidden, p.hidden, p.A, nullptr);
    bmm_kernel<H, 8, false><<<bg, 256, 0, stream>>>(p.hh2, p.hidden, p.hh1, p.A, nullptr);
    gsgt_nv_kernel<<<(B * N * E) / 256, 256, 0, stream>>>(
        p.hidden, p.hh1, p.hh2, p.Wa1, p.ba1, p.Wa2, p.ba2, graph, gstride,
        p.Wsrc, p.bsrc, p.Wtgt, p.btgt, p.nvs, p.nvt);
    adp_kernel<<<dim3(N, B), 512, 0, stream>>>(p.nvs, p.nvt, p.adp);
    concat_kernel<<<(B * N * CC) / 256, 256, 0, stream>>>(graph, gstride, p.hidden, p.comb);
    bmm_kernel<CC, 9, true><<<bg, 256, 0, stream>>>(p.hr1, p.comb, p.comb, p.A, p.adp);
    bmm_kernel<CC, 9, true><<<bg, 256, 0, stream>>>(p.hr2, p.comb, p.hr1, p.A, p.adp);
    zr_kernel<<<(B * N * H) / 256, 256, 0, stream>>>(
        p.comb, p.hr1, p.hr2, p.Wgz, p.bgz, p.Wgr, p.bgr, p.hidden, graph, gstride,
        p.z, p.comb2);
    bmm_kernel<CC, 9, true><<<bg, 256, 0, stream>>>(p.hr1, p.comb2, p.comb2, p.A, p.adp);
    bmm_kernel<CC, 9, true><<<bg, 256, 0, stream>>>(p.hr2, p.comb2, p.hr1, p.A, p.adp);
    c_update_kernel<<<(B * N * H) / 256, 256, 0, stream>>>(
        p.comb2, p.hr1, p.hr2, p.Wgc, p.bgc, p.z, p.hidden);
}
}  // namespace

extern "C" void kernel_launch(void* const* d_in, const int* in_sizes, int n_in,
                              void* d_out, int out_size, void* d_ws, size_t ws_size,
                              hipStream_t stream)
{
    (void)in_sizes; (void)n_in; (void)out_size; (void)ws_size;
    Ptrs p;
    p.sample = (const float*)d_in[0];
    p.A      = (const float*)d_in[1];
    p.wq     = (const float*)d_in[2];
    p.wk     = (const float*)d_in[3];
    p.attn_bias  = (const float*)d_in[4];
    p.attn_trans = (const float*)d_in[5];
    p.Wt  = (const float*)d_in[6];
    p.bt_ = (const float*)d_in[7];
    p.Wa1 = (const float*)d_in[8];
    p.ba1 = (const float*)d_in[9];
    p.Wa2 = (const float*)d_in[10];
    p.ba2 = (const float*)d_in[11];
    p.Wsrc = (const float*)d_in[12];
    p.bsrc = (const float*)d_in[13];
    p.Wtgt = (const float*)d_in[14];
    p.btgt = (const float*)d_in[15];
    p.Wgz = (const float*)d_in[16];
    p.bgz = (const float*)d_in[17];
    p.Wgr = (const float*)d_in[18];
    p.bgr = (const float*)d_in[19];
    p.Wgc = (const float*)d_in[20];
    p.bgc = (const float*)d_in[21];
    p.Wsh = (const float*)d_in[22];
    p.bsh = (const float*)d_in[23];
    p.Wl  = (const float*)d_in[24];
    p.bl  = (const float*)d_in[25];
    p.Wm  = (const float*)d_in[26];
    p.bm  = (const float*)d_in[27];

    float* ws = (float*)d_ws;
    size_t off = 0;
    auto alloc = [&](size_t nelem) { float* r = ws + off; off += nelem; return r; };
    p.hidden = alloc((size_t)B * N * H);
    p.hh1    = alloc((size_t)B * N * H);
    p.hh2    = alloc((size_t)B * N * H);
    p.nvs    = alloc((size_t)B * N * E);
    p.nvt    = alloc((size_t)B * N * E);
    p.adp    = alloc((size_t)B * N * N);
    p.comb   = alloc((size_t)B * N * CC);
    p.hr1    = alloc((size_t)B * N * CC);
    p.hr2    = alloc((size_t)B * N * CC);
    p.z      = alloc((size_t)B * N * H);
    p.comb2  = alloc((size_t)B * N * CC);
    p.q      = alloc((size_t)B * N * DA);
    p.kk     = alloc((size_t)B * 4 * N * DA);
    p.th1    = alloc((size_t)B * 4 * N * F);
    p.th2    = alloc((size_t)B * 4 * N * F);
    p.tar32  = alloc((size_t)B * N * TGN_OC);

    float* out = (float*)d_out;
    float* out_gat = out;                      // (B,N,F)
    float* out_gru = out + (size_t)B * N * F;  // (B,N,F)
    float* out_fin = out + (size_t)2 * B * N * F;
    float* out_attn = out + (size_t)3 * B * N * F;  // (B,4,N,N)

    hipMemsetAsync(p.hidden, 0, (size_t)B * N * H * sizeof(float), stream);

    // 5 scan steps: graph_i = sample[:, 4*i]
    for (int i = 0; i < 5; ++i) {
        const float* graph = p.sample + (size_t)(4 * i) * N * F;
        gru_step(stream, p, graph, (long)T * N * F);
    }

    // attention + TGN
    qk_kernel<<<(B * N * DA + B * 4 * N * DA) / 256, 256, 0, stream>>>(
        p.sample, p.wq, p.wk, p.attn_bias, p.q, p.kk);
    scores_kernel<<<dim3(N, 4, B), 512, 0, stream>>>(p.q, p.kk, p.attn_trans, out_attn);

    const float* srcbase = p.sample + (size_t)(T - 4) * N * F;
    tgn_mm_kernel<<<dim3(N / 64, B * 4), 128, 0, stream>>>(
        p.A, out_attn, srcbase, (long)T * N * F, (long)N * F,
        srcbase, (long)T * N * F, (long)N * F, p.th1);
    tgn_mm_kernel<<<dim3(N / 64, B * 4), 128, 0, stream>>>(
        p.A, out_attn, p.th1, (long)4 * N * F, (long)N * F,
        srcbase, (long)T * N * F, (long)N * F, p.th2);
    tgn_out_kernel<<<(B * N * TGN_OC) / 256, 256, 0, stream>>>(
        p.sample, p.th1, p.th2, p.Wt, p.bt_, p.tar32);
    gat_kernel<<<(B * N * F) / 256, 256, 0, stream>>>(p.tar32, p.Wsh, p.bsh, out_gat);

    // final GRU step with graph = gat_result (contiguous in d_out)
    gru_step(stream, p, out_gat, (long)N * F);

    final_kernel<<<(B * N * F) / 256, 256, 0, stream>>>(
        p.hidden, p.tar32, p.Wl, p.bl, p.Wm, p.bm, out_gru, out_fin);
}